// Round 1
// baseline (1685.014 us; speedup 1.0000x reference)
//
#include <hip/hip_runtime.h>

#define N_NODES 50000
#define D_DIM   256
#define N_BATCH 4

// ---------------- small helpers ----------------
__device__ inline float4 fma4(float a, float4 b, float4 c) {
    c.x = fmaf(a, b.x, c.x);
    c.y = fmaf(a, b.y, c.y);
    c.z = fmaf(a, b.z, c.z);
    c.w = fmaf(a, b.w, c.w);
    return c;
}

// ---------------- CSR build ----------------
__global__ void zero_kernel(int* __restrict__ p, int n) {
    int i = blockIdx.x * 256 + threadIdx.x;
    if (i < n) p[i] = 0;
}

__global__ void hist_kernel(const int* __restrict__ rows, int* __restrict__ counts, int E) {
    int e = blockIdx.x * 256 + threadIdx.x;
    if (e < E) atomicAdd(&counts[rows[e]], 1);
}

// Single-block exclusive scan over counts[n] -> starts[n+1], cursor[n].
// 1024 threads; wave-level shfl scan + 16-wave LDS scan; carry across chunks.
__global__ void scan_kernel(const int* __restrict__ counts, int* __restrict__ starts,
                            int* __restrict__ cursor, int n) {
    __shared__ int wsum[16];
    __shared__ int btot;
    const int tid  = threadIdx.x;      // 0..1023
    const int lane = tid & 63;
    const int wid  = tid >> 6;         // 0..15
    int carry = 0;
    for (int base = 0; base < n; base += 1024) {
        int i = base + tid;
        int v = (i < n) ? counts[i] : 0;
        // intra-wave inclusive scan
        int x = v;
        #pragma unroll
        for (int s = 1; s < 64; s <<= 1) {
            int y = __shfl_up(x, s, 64);
            if (lane >= s) x += y;
        }
        if (lane == 63) wsum[wid] = x;
        __syncthreads();
        if (wid == 0 && lane < 16) {
            int w  = wsum[lane];
            int xx = w;
            #pragma unroll
            for (int s = 1; s < 16; s <<= 1) {
                int y = __shfl_up(xx, s, 64);
                if (lane >= s) xx += y;
            }
            wsum[lane] = xx - w;        // exclusive wave offsets
            if (lane == 15) btot = xx;  // chunk total
        }
        __syncthreads();
        int excl = carry + wsum[wid] + x - v;
        if (i < n) { starts[i] = excl; cursor[i] = excl; }
        carry += btot;
        __syncthreads();                // protect wsum/btot before next chunk
    }
    if (tid == 0) starts[n] = carry;
}

__global__ void scatter_kernel(const int* __restrict__ rows, const int* __restrict__ cols,
                               const float* __restrict__ vals, int* __restrict__ cursor,
                               int2* __restrict__ csr, int E) {
    int e = blockIdx.x * 256 + threadIdx.x;
    if (e < E) {
        int r   = rows[e];
        int pos = atomicAdd(&cursor[r], 1);
        csr[pos] = make_int2(cols[e], __float_as_int(vals[e]));
    }
}

// ---------------- dense GEMM: S[M,256] = X[M,256] @ W[256,256] ----------------
// 128x128 tile, KC=32 LDS chunks, 256 threads, 8x8 (as 8 rows x 2 float4) micro-tile.
// LDS: xs 128x36 (pad 4 -> 2-way max bank aliasing, free) + ws_t 32x128 = 34.8 KB -> 4 blocks/CU.
#define BM 128
#define BN 128
#define KC 32
__global__ __launch_bounds__(256, 4) void gemm_kernel(const float* __restrict__ X,
                                                      const float* __restrict__ W,
                                                      float* __restrict__ S, int M) {
    __shared__ float xs[BM * 36];      // [row][k], stride 36 floats (144 B, 16B-aligned)
    __shared__ float ws_t[KC * BN];    // [k][col], stride 128

    const int tid = threadIdx.x;
    const int colTile = blockIdx.x & 1;      // 256/BN = 2 col tiles
    const int rowTile = blockIdx.x >> 1;
    const int row0 = rowTile * BM;
    const int col0 = colTile * BN;
    const int tx = tid & 15;                 // col group
    const int ty = tid >> 4;                 // row group

    float4 acc[8][2];
    #pragma unroll
    for (int n = 0; n < 8; ++n) { acc[n][0] = make_float4(0,0,0,0); acc[n][1] = make_float4(0,0,0,0); }

    for (int kc = 0; kc < D_DIM; kc += KC) {
        // stage X tile: 128 rows x 32 k = 1024 float4, 4 per thread
        #pragma unroll
        for (int it = 0; it < 4; ++it) {
            int j   = it * 256 + tid;
            int kq  = j & 7;                 // 8 f4 per row
            int row = j >> 3;
            int gr  = row0 + row; if (gr >= M) gr = M - 1;
            float4 v = ((const float4*)X)[(size_t)gr * (D_DIM/4) + (kc >> 2) + kq];
            *((float4*)&xs[row * 36 + kq * 4]) = v;
        }
        // stage W tile: 32 k x 128 cols = 1024 float4
        #pragma unroll
        for (int it = 0; it < 4; ++it) {
            int j  = it * 256 + tid;
            int cq = j & 31;                 // 32 f4 per k-row
            int k  = j >> 5;
            float4 v = ((const float4*)W)[(size_t)(kc + k) * (D_DIM/4) + (col0 >> 2) + cq];
            *((float4*)&ws_t[k * BN + cq * 4]) = v;
        }
        __syncthreads();
        #pragma unroll 2
        for (int k = 0; k < KC; ++k) {
            float4 w0 = ((const float4*)&ws_t[k * BN])[tx];
            float4 w1 = ((const float4*)&ws_t[k * BN])[16 + tx];
            #pragma unroll
            for (int n = 0; n < 8; ++n) {
                float a = xs[(ty + 16 * n) * 36 + k];
                acc[n][0] = fma4(a, w0, acc[n][0]);
                acc[n][1] = fma4(a, w1, acc[n][1]);
            }
        }
        __syncthreads();
    }
    // store: rows ty+16n, cols col0 + 4*tx and col0 + 64 + 4*tx
    #pragma unroll
    for (int n = 0; n < 8; ++n) {
        int gr = row0 + ty + 16 * n;
        if (gr < M) {
            ((float4*)S)[(size_t)gr * (D_DIM/4) + (col0 >> 2) + tx]      = acc[n][0];
            ((float4*)S)[(size_t)gr * (D_DIM/4) + (col0 >> 2) + 16 + tx] = acc[n][1];
        }
    }
}

// ---------------- SpMM: out[b,r,:] = sum_e val*support[b,col,:] + bias ----------------
// One block per row; wave w handles batch w (block = 64*nbatch threads).
// Each lane owns a float4 (256 floats / 64 lanes). No atomics; bias fused.
__global__ void spmm_kernel(const float* __restrict__ support,
                            const int* __restrict__ starts,
                            const int2* __restrict__ csr,
                            const float* __restrict__ bias,
                            float* __restrict__ out, int nnodes) {
    const int row  = blockIdx.x;
    const int wave = threadIdx.x >> 6;   // batch index
    const int lane = threadIdx.x & 63;
    const float4* sup4 = (const float4*)support + (size_t)wave * nnodes * (D_DIM/4);
    const int s = starts[row];
    const int e = starts[row + 1];
    float4 acc = make_float4(0,0,0,0);
    int i = s;
    for (; i + 1 < e; i += 2) {   // unroll-2 for memory-level parallelism
        int2 e0 = csr[i];
        int2 e1 = csr[i + 1];
        float4 g0 = sup4[(size_t)e0.x * (D_DIM/4) + lane];
        float4 g1 = sup4[(size_t)e1.x * (D_DIM/4) + lane];
        acc = fma4(__int_as_float(e0.y), g0, acc);
        acc = fma4(__int_as_float(e1.y), g1, acc);
    }
    if (i < e) {
        int2 e0 = csr[i];
        float4 g0 = sup4[(size_t)e0.x * (D_DIM/4) + lane];
        acc = fma4(__int_as_float(e0.y), g0, acc);
    }
    float4 bb = ((const float4*)bias)[lane];
    acc.x += bb.x; acc.y += bb.y; acc.z += bb.z; acc.w += bb.w;
    float4* o4 = (float4*)out + (size_t)wave * nnodes * (D_DIM/4);
    o4[(size_t)row * (D_DIM/4) + lane] = acc;
}

// ---------------- launch ----------------
extern "C" void kernel_launch(void* const* d_in, const int* in_sizes, int n_in,
                              void* d_out, int out_size, void* d_ws, size_t ws_size,
                              hipStream_t stream) {
    const float* X    = (const float*)d_in[0];
    const int*   rows = (const int*)d_in[1];
    const int*   cols = (const int*)d_in[2];
    const float* vals = (const float*)d_in[3];
    const float* W    = (const float*)d_in[4];
    const float* bias = (const float*)d_in[5];
    float*       out  = (float*)d_out;
    const int E = in_sizes[1];

    // workspace layout (256 B aligned regions)
    char* wsb = (char*)d_ws;
    size_t o = 0;
    auto alloc = [&](size_t bytes) -> char* {
        char* p = wsb + o;
        o += (bytes + 255) & ~(size_t)255;
        return p;
    };
    int*  counts = (int*)alloc((size_t)N_NODES * 4);
    int*  starts = (int*)alloc((size_t)(N_NODES + 1) * 4);
    int*  cursor = (int*)alloc((size_t)N_NODES * 4);
    int2* csr    = (int2*)alloc((size_t)E * 8);
    const size_t fixed = o;

    // CSR build (graph is identical across batches — build once)
    zero_kernel<<<(N_NODES + 255) / 256, 256, 0, stream>>>(counts, N_NODES);
    hist_kernel<<<(E + 255) / 256, 256, 0, stream>>>(rows, counts, E);
    scan_kernel<<<1, 1024, 0, stream>>>(counts, starts, cursor, N_NODES);
    scatter_kernel<<<(E + 255) / 256, 256, 0, stream>>>(rows, cols, vals, cursor, csr, E);

    const size_t full_sup = (size_t)N_BATCH * N_NODES * D_DIM * 4;
    if (ws_size >= fixed + full_sup) {
        float* support = (float*)alloc(full_sup);
        const int M = N_BATCH * N_NODES;                  // 200000
        const int rowTiles = (M + BM - 1) / BM;
        gemm_kernel<<<rowTiles * 2, 256, 0, stream>>>(X, W, support, M);
        spmm_kernel<<<N_NODES, 64 * N_BATCH, 0, stream>>>(support, starts, csr, bias, out, N_NODES);
    } else {
        // per-batch fallback: support = 51.2 MB
        float* support = (float*)alloc((size_t)N_NODES * D_DIM * 4);
        const int rowTiles = (N_NODES + BM - 1) / BM;
        for (int b = 0; b < N_BATCH; ++b) {
            gemm_kernel<<<rowTiles * 2, 256, 0, stream>>>(X + (size_t)b * N_NODES * D_DIM, W, support, N_NODES);
            spmm_kernel<<<N_NODES, 64, 0, stream>>>(support, starts, csr, bias,
                                                    out + (size_t)b * N_NODES * D_DIM, N_NODES);
        }
    }
}

// Round 2
// 1070.649 us; speedup vs baseline: 1.5738x; 1.5738x over previous
//
#include <hip/hip_runtime.h>

#define N_NODES 50000
#define D_DIM   256
#define N_BATCH 4
#define M_TOTAL (N_BATCH * N_NODES)

typedef __attribute__((ext_vector_type(8))) short bf16x8;  // 8 bf16 = 4 VGPRs
typedef __attribute__((ext_vector_type(4))) float f32x4;

// ---------------- small helpers ----------------
__device__ inline float4 fma4(float a, float4 b, float4 c) {
    c.x = fmaf(a, b.x, c.x);
    c.y = fmaf(a, b.y, c.y);
    c.z = fmaf(a, b.z, c.z);
    c.w = fmaf(a, b.w, c.w);
    return c;
}

__device__ inline unsigned short f2bf(float f) {  // round-nearest-even fp32->bf16
    unsigned u = __float_as_uint(f);
    u = (u + 0x7fffu + ((u >> 16) & 1u)) >> 16;
    return (unsigned short)u;
}

__device__ inline float4 bf4tof4(ushort4 v) {
    return make_float4(__uint_as_float((unsigned)v.x << 16),
                       __uint_as_float((unsigned)v.y << 16),
                       __uint_as_float((unsigned)v.z << 16),
                       __uint_as_float((unsigned)v.w << 16));
}

// async global->LDS, 16B per lane; lds dest = uniform base + lane*16
__device__ inline void async_copy16(const unsigned short* g, unsigned short* l) {
    __builtin_amdgcn_global_load_lds(
        (const __attribute__((address_space(1))) char*)g,
        (__attribute__((address_space(3))) char*)l, 16, 0, 0);
}

// ---------------- CSR build ----------------
__global__ void zero_kernel(int* __restrict__ p, int n) {
    int i = blockIdx.x * 256 + threadIdx.x;
    if (i < n) p[i] = 0;
}

__global__ void hist_kernel(const int* __restrict__ rows, int* __restrict__ counts, int E) {
    int e = blockIdx.x * 256 + threadIdx.x;
    if (e < E) atomicAdd(&counts[rows[e]], 1);
}

// Single-block exclusive scan over counts[n] -> starts[n+1], cursor[n].
__global__ void scan_kernel(const int* __restrict__ counts, int* __restrict__ starts,
                            int* __restrict__ cursor, int n) {
    __shared__ int wsum[16];
    __shared__ int btot;
    const int tid  = threadIdx.x;      // 0..1023
    const int lane = tid & 63;
    const int wid  = tid >> 6;         // 0..15
    int carry = 0;
    for (int base = 0; base < n; base += 1024) {
        int i = base + tid;
        int v = (i < n) ? counts[i] : 0;
        int x = v;
        #pragma unroll
        for (int s = 1; s < 64; s <<= 1) {
            int y = __shfl_up(x, s, 64);
            if (lane >= s) x += y;
        }
        if (lane == 63) wsum[wid] = x;
        __syncthreads();
        if (wid == 0 && lane < 16) {
            int w  = wsum[lane];
            int xx = w;
            #pragma unroll
            for (int s = 1; s < 16; s <<= 1) {
                int y = __shfl_up(xx, s, 64);
                if (lane >= s) xx += y;
            }
            wsum[lane] = xx - w;
            if (lane == 15) btot = xx;
        }
        __syncthreads();
        int excl = carry + wsum[wid] + x - v;
        if (i < n) { starts[i] = excl; cursor[i] = excl; }
        carry += btot;
        __syncthreads();
    }
    if (tid == 0) starts[n] = carry;
}

__global__ void scatter_kernel(const int* __restrict__ rows, const int* __restrict__ cols,
                               const float* __restrict__ vals, int* __restrict__ cursor,
                               int2* __restrict__ csr, int E) {
    int e = blockIdx.x * 256 + threadIdx.x;
    if (e < E) {
        int r   = rows[e];
        int pos = atomicAdd(&cursor[r], 1);
        csr[pos] = make_int2(cols[e], __float_as_int(vals[e]));
    }
}

// ---------------- casts ----------------
__global__ void cast_x_kernel(const float4* __restrict__ X, ushort4* __restrict__ Xb, int n4) {
    int i = blockIdx.x * 256 + threadIdx.x;
    if (i < n4) {
        float4 v = X[i];
        ushort4 o;
        o.x = f2bf(v.x); o.y = f2bf(v.y); o.z = f2bf(v.z); o.w = f2bf(v.w);
        Xb[i] = o;
    }
}

// Wt[n][k] = W[k][n], bf16
__global__ void cast_wt_kernel(const float* __restrict__ W, unsigned short* __restrict__ Wt) {
    int i = blockIdx.x * 256 + threadIdx.x;   // 65536 total
    int n = i >> 8, k = i & 255;
    Wt[n * 256 + k] = f2bf(W[k * 256 + n]);
}

// ---------------- MFMA GEMM: sup[node][batch][256] (bf16) = Xb[M,256] @ W ----------------
// 128x128 tile, 4 waves in 2x2, each wave 4x4 of 16x16x32 MFMA tiles, BK=32.
// Operands swapped (mfma(B,A,acc)) so D[row=n][col=m]: each lane stores 4 consecutive
// output cols (ushort4, 8B) at one output row -> coalesced-ish epilogue.
__global__ __launch_bounds__(256) void gemm_mfma_kernel(const unsigned short* __restrict__ Xb,
                                                        const unsigned short* __restrict__ Wt,
                                                        unsigned short* __restrict__ sup) {
    __shared__ unsigned short at[128 * 32];   // [row][k], row stride 64B
    __shared__ unsigned short bt[128 * 32];   // [n][k]
    const int tid  = threadIdx.x;
    const int lane = tid & 63;
    const int wid  = tid >> 6;
    const int wm   = wid & 1, wn = wid >> 1;
    const int row0 = (blockIdx.x >> 1) * 128;
    const int col0 = (blockIdx.x & 1) * 128;
    const int fr    = lane & 15;          // fragment row index
    const int fk    = (lane >> 4) * 8;    // fragment k offset
    const int srow  = lane >> 2;          // staging sub-row 0..15
    const int skoff = (lane & 3) * 8;     // staging k offset (ushorts)

    f32x4 acc[4][4];
    #pragma unroll
    for (int a = 0; a < 4; ++a)
        #pragma unroll
        for (int b = 0; b < 4; ++b) acc[a][b] = (f32x4){0.f, 0.f, 0.f, 0.f};

    for (int kc = 0; kc < 256; kc += 32) {
        #pragma unroll
        for (int c = 0; c < 2; ++c) {
            int r = wid * 32 + c * 16;                 // chunk base row (uniform per wave)
            int gra = row0 + r + srow; if (gra >= M_TOTAL) gra = M_TOTAL - 1;
            async_copy16(Xb + (size_t)gra * 256 + kc + skoff, &at[r * 32]);
            int grb = col0 + r + srow;
            async_copy16(Wt + (size_t)grb * 256 + kc + skoff, &bt[r * 32]);
        }
        __syncthreads();   // drains vmcnt for global_load_lds
        bf16x8 af[4], bfr[4];
        #pragma unroll
        for (int t = 0; t < 4; ++t) {
            af[t]  = *(const bf16x8*)&at[(wm * 64 + t * 16 + fr) * 32 + fk];
            bfr[t] = *(const bf16x8*)&bt[(wn * 64 + t * 16 + fr) * 32 + fk];
        }
        #pragma unroll
        for (int tn = 0; tn < 4; ++tn)
            #pragma unroll
            for (int tm = 0; tm < 4; ++tm)
                acc[tn][tm] = __builtin_amdgcn_mfma_f32_16x16x32_bf16(bfr[tn], af[tm], acc[tn][tm], 0, 0, 0);
        __syncthreads();
    }

    // epilogue: D[row=n][col=m]; lane holds output row m = ...+fr, cols n0..n0+3
    #pragma unroll
    for (int tm = 0; tm < 4; ++tm) {
        int gr = row0 + wm * 64 + tm * 16 + fr;        // flattened b*N_NODES+node
        if (gr < M_TOTAL) {
            int b    = (int)((unsigned)gr / (unsigned)N_NODES);
            int node = gr - b * N_NODES;
            size_t base = ((size_t)node * 4 + b) * 256;
            #pragma unroll
            for (int tn = 0; tn < 4; ++tn) {
                int col = col0 + wn * 64 + tn * 16 + (lane >> 4) * 4;
                ushort4 o;
                o.x = f2bf(acc[tn][tm][0]);
                o.y = f2bf(acc[tn][tm][1]);
                o.z = f2bf(acc[tn][tm][2]);
                o.w = f2bf(acc[tn][tm][3]);
                *(ushort4*)&sup[base + col] = o;
            }
        }
    }
}

// ---------------- SpMM: out[b,r,:] = sum_e val * sup[col_e][b][:] + bias ----------------
// One block per node row; wave = batch; lane owns 4 cols. Per edge one 2KB
// contiguous block read (all 4 batches). No atomics; bias fused.
__global__ __launch_bounds__(256) void spmm_kernel(const unsigned short* __restrict__ sup,
                                                   const int* __restrict__ starts,
                                                   const int2* __restrict__ csr,
                                                   const float* __restrict__ bias,
                                                   float* __restrict__ out) {
    const int row  = blockIdx.x;
    const int b    = threadIdx.x >> 6;
    const int lane = threadIdx.x & 63;
    const unsigned short* supb = sup + (size_t)b * 256 + (size_t)lane * 4;
    const int s = starts[row];
    const int e = starts[row + 1];
    float4 acc = make_float4(0.f, 0.f, 0.f, 0.f);
    int i = s;
    for (; i + 3 < e; i += 4) {     // unroll-4 for memory-level parallelism
        int2 e0 = csr[i], e1 = csr[i + 1], e2 = csr[i + 2], e3 = csr[i + 3];
        ushort4 v0 = *(const ushort4*)(supb + (size_t)e0.x * 1024);
        ushort4 v1 = *(const ushort4*)(supb + (size_t)e1.x * 1024);
        ushort4 v2 = *(const ushort4*)(supb + (size_t)e2.x * 1024);
        ushort4 v3 = *(const ushort4*)(supb + (size_t)e3.x * 1024);
        acc = fma4(__int_as_float(e0.y), bf4tof4(v0), acc);
        acc = fma4(__int_as_float(e1.y), bf4tof4(v1), acc);
        acc = fma4(__int_as_float(e2.y), bf4tof4(v2), acc);
        acc = fma4(__int_as_float(e3.y), bf4tof4(v3), acc);
    }
    for (; i < e; ++i) {
        int2 e0 = csr[i];
        ushort4 v0 = *(const ushort4*)(supb + (size_t)e0.x * 1024);
        acc = fma4(__int_as_float(e0.y), bf4tof4(v0), acc);
    }
    float4 bb = ((const float4*)bias)[lane];
    acc.x += bb.x; acc.y += bb.y; acc.z += bb.z; acc.w += bb.w;
    ((float4*)out)[((size_t)b * N_NODES + row) * (D_DIM / 4) + lane] = acc;
}

// ---------------- launch ----------------
extern "C" void kernel_launch(void* const* d_in, const int* in_sizes, int n_in,
                              void* d_out, int out_size, void* d_ws, size_t ws_size,
                              hipStream_t stream) {
    const float* X    = (const float*)d_in[0];
    const int*   rows = (const int*)d_in[1];
    const int*   cols = (const int*)d_in[2];
    const float* vals = (const float*)d_in[3];
    const float* W    = (const float*)d_in[4];
    const float* bias = (const float*)d_in[5];
    float*       out  = (float*)d_out;
    const int E = in_sizes[1];

    char* wsb = (char*)d_ws;
    size_t o = 0;
    auto alloc = [&](size_t bytes) -> char* {
        char* p = wsb + o;
        o += (bytes + 255) & ~(size_t)255;
        return p;
    };
    int*  counts = (int*)alloc((size_t)N_NODES * 4);
    int*  starts = (int*)alloc((size_t)(N_NODES + 1) * 4);
    int*  cursor = (int*)alloc((size_t)N_NODES * 4);           // reused as Wt after scatter
    int2* csr    = (int2*)alloc((size_t)E * 8);
    unsigned short* Xb  = (unsigned short*)alloc((size_t)M_TOTAL * D_DIM * 2);   // 102.4 MB
    unsigned short* sup = (unsigned short*)alloc((size_t)N_NODES * N_BATCH * D_DIM * 2); // 102.4 MB
    unsigned short* Wt  = (unsigned short*)cursor;             // 128 KB < 200 KB cursor region

    // CSR build (graph identical across batches — build once)
    zero_kernel<<<(N_NODES + 255) / 256, 256, 0, stream>>>(counts, N_NODES);
    hist_kernel<<<(E + 255) / 256, 256, 0, stream>>>(rows, counts, E);
    scan_kernel<<<1, 1024, 0, stream>>>(counts, starts, cursor, N_NODES);
    scatter_kernel<<<(E + 255) / 256, 256, 0, stream>>>(rows, cols, vals, cursor, csr, E);

    // casts (cast_wt AFTER scatter: it overwrites cursor)
    const int n4 = M_TOTAL * D_DIM / 4;
    cast_x_kernel<<<(n4 + 255) / 256, 256, 0, stream>>>((const float4*)X, (ushort4*)Xb, n4);
    cast_wt_kernel<<<(256 * 256) / 256, 256, 0, stream>>>(W, Wt);

    // GEMM -> sup (bf16, [node][batch][256])
    const int rowTiles = (M_TOTAL + 127) / 128;
    gemm_mfma_kernel<<<rowTiles * 2, 256, 0, stream>>>(Xb, Wt, sup);

    // SpMM + bias
    spmm_kernel<<<N_NODES, 256, 0, stream>>>(sup, starts, csr, bias, out);
}